// Round 7
// baseline (816.322 us; speedup 1.0000x reference)
//
#include <hip/hip_runtime.h>
#include <hip/hip_bf16.h>

// Problem constants (match reference)
#define NNODES 100000
#define NEDGES 3200000
#define INDIM  512
#define HID    128
#define NCLS   64

#define CHUNK  4096
#define NCHUNKB ((NEDGES + CHUNK - 1) / CHUNK)   // 782 edge blocks

#define ECSR_CAP (4u << 20)                // 4M int2 entries; sum pad8(deg) <= 3.9M
#define NSCAN    ((NNODES + 511) / 512)    // 196 scan blocks

typedef __bf16 bf16x8 __attribute__((ext_vector_type(8)));
typedef __bf16 bf16x4 __attribute__((ext_vector_type(4)));
typedef float  f32x4  __attribute__((ext_vector_type(4)));

#define HPAD 136   // h0s row pad (272B stride; 68 words %32=4)

// ---------------------------------------------------------------------------
// Fused: blocks 0..NCHUNKB-1 = per-node degree count (global atomics, deg is
// 400KB L2-resident); block NCHUNKB = weight conversion into MFMA-FRAGMENT-
// PACKED order:
// W0P[((kk*8+t)*64+lane)*8 + j] = W0[(kk*32+(lane>>4)*8+j)*HID + t*16+(lane&15)]
// ---------------------------------------------------------------------------
__global__ __launch_bounds__(256)
void k_count_wcvt(const int* __restrict__ dst, int* __restrict__ deg,
                  const float* __restrict__ W0, const float* __restrict__ W1,
                  __bf16* __restrict__ W0P, __bf16* __restrict__ W1P) {
  const int t = threadIdx.x;
  if (blockIdx.x == NCHUNKB) {
    for (int i = t; i < 65536; i += 256) {      // W0 [512][128] -> packed
      const int c = i >> 3, j = i & 7;
      const int ln = c & 63, tt = (c >> 6) & 7, kk = c >> 9;
      const int row = tt * 16 + (ln & 15);
      const int k   = kk * 32 + (ln >> 4) * 8 + j;
      W0P[i] = (__bf16)W0[k * HID + row];
    }
    for (int i = t; i < 8192; i += 256) {       // W1 [128][64] -> packed
      const int c = i >> 3, j = i & 7;
      const int ln = c & 63, tt = (c >> 6) & 3, kk = c >> 8;
      const int row = tt * 16 + (ln & 15);
      const int k   = kk * 32 + (ln >> 4) * 8 + j;
      W1P[i] = (__bf16)W1[k * NCLS + row];
    }
    return;
  }
  const int base = blockIdx.x * CHUNK;
#pragma unroll
  for (int j = 0; j < CHUNK / 1024; ++j) {
    const int e = base + (j * 256 + t) * 4;
    if (e < NEDGES) {                           // NEDGES%4==0 => full int4 ok
      const int4 d = *(const int4*)&dst[e];
      atomicAdd(&deg[d.x], 1);
      atomicAdd(&deg[d.y], 1);
      atomicAdd(&deg[d.z], 1);
      atomicAdd(&deg[d.w], 1);
    }
  }
}

// ---------------------------------------------------------------------------
// Per-512-node-block pad8 prefix scan. Each block reserves its ecsr segment
// with ONE atomicAdd on a global allocator (segment order across blocks is
// irrelevant -> no device-wide scan needed). Writes rowinfo{base,pdeg} and
// the scatter cursor cur=base. pad8 bases keep ecsr int4 loads 16B-aligned.
// ---------------------------------------------------------------------------
__global__ __launch_bounds__(512)
void k_lscan(const int* __restrict__ deg, int* __restrict__ galloc,
             int2* __restrict__ rowinfo, int* __restrict__ cur) {
  __shared__ int s[512];
  __shared__ int segbase;
  const int t = threadIdx.x;
  const int n = blockIdx.x * 512 + t;
  const int d  = (n < NNODES) ? deg[n] : 0;
  const int pd = (d + 7) & ~7;
  s[t] = pd;
  __syncthreads();
  for (int off = 1; off < 512; off <<= 1) {
    int x = (t >= off) ? s[t - off] : 0;
    __syncthreads();
    s[t] += x;
    __syncthreads();
  }
  if (t == 511) segbase = atomicAdd(galloc, s[511]);
  __syncthreads();
  if (n < NNODES) {
    const int st = segbase + s[t] - pd;
    rowinfo[n] = make_int2(st, pd);
    cur[n] = st;
  }
}

// ---------------------------------------------------------------------------
// Fused dispatch: blocks 0..NCHUNKB-1 = edge scatter DIRECTLY into final CSR
// (p = atomicAdd(&cur[dst],1); ecsr[p] = {src,val}; padding gaps pre-zeroed
// by memset). blocks NCHUNKB.. = dense GEMM h1 = relu(X@W0)@W1 (bf16 MFMA).
// GEMM: B fragments from fragment-packed W0P/W1P (coalesced 1KB wave-loads),
// depth-2 A-prefetch rotation, no barriers; LDS = 17.4KB h0s relay only.
// ---------------------------------------------------------------------------
__global__ __launch_bounds__(256, 4)
void k_scatter_gemm(const int* __restrict__ dst, const int* __restrict__ src,
                    const float* __restrict__ val, int* __restrict__ cur,
                    int2* __restrict__ ecsr,
                    const float* __restrict__ feat, const __bf16* __restrict__ W0P,
                    const __bf16* __restrict__ W1P, __bf16* __restrict__ h1b) {
  __shared__ __align__(16) char smem[64 * HPAD * 2];   // 17,408 B
  const int tid = threadIdx.x;

  if (blockIdx.x < NCHUNKB) {
    // ---------------- scatter branch ----------------
    const int base = blockIdx.x * CHUNK;
#pragma unroll
    for (int j = 0; j < CHUNK / 1024; ++j) {
      const int e = base + (j * 256 + tid) * 4;
      if (e < NEDGES) {
        const int4   d  = *(const int4*)&dst[e];
        const int4   sc = *(const int4*)&src[e];
        const float4 vv = *(const float4*)&val[e];
        int p;
        p = atomicAdd(&cur[d.x], 1);
        ecsr[p] = make_int2(sc.x, __float_as_int(vv.x));
        p = atomicAdd(&cur[d.y], 1);
        ecsr[p] = make_int2(sc.y, __float_as_int(vv.y));
        p = atomicAdd(&cur[d.z], 1);
        ecsr[p] = make_int2(sc.z, __float_as_int(vv.z));
        p = atomicAdd(&cur[d.w], 1);
        ecsr[p] = make_int2(sc.w, __float_as_int(vv.w));
      }
    }
    return;
  }

  // ---------------- gemm branch (4 waves, 64 rows) ----------------
  __bf16* h0s = (__bf16*)smem;                 // [64][HPAD] per-wave stripes

  const int wave = tid >> 6;
  const int lane = tid & 63;
  const int q    = lane >> 4;
  const int l16  = lane & 15;
  const int rb   = (blockIdx.x - NCHUNKB) * 64;

  int row = rb + wave * 16 + l16;
  if (row >= NNODES) row = NNODES - 1;          // clamped loads; stores guarded
  const float4* __restrict__ arow4 =
      (const float4*)(feat + (size_t)row * INDIM);  // 128 float4 per row

  f32x4 acc[8];
#pragma unroll
  for (int t = 0; t < 8; ++t) acc[t] = (f32x4){0.f, 0.f, 0.f, 0.f};

  // Depth-2 A-prefetch pipeline: pa = a[kk], qa = a[kk+1], na = a[kk+2].
  float4 pa0 = arow4[q * 2],     pa1 = arow4[q * 2 + 1];
  float4 qa0 = arow4[8 + q * 2], qa1 = arow4[8 + q * 2 + 1];

#pragma unroll 2
  for (int kk = 0; kk < INDIM / 32; ++kk) {
    float4 na0 = pa0, na1 = pa1;
    if (kk < INDIM / 32 - 2) {
      na0 = arow4[(kk + 2) * 8 + q * 2];
      na1 = arow4[(kk + 2) * 8 + q * 2 + 1];
    }
    bf16x8 aF;
    aF[0] = (__bf16)pa0.x; aF[1] = (__bf16)pa0.y; aF[2] = (__bf16)pa0.z; aF[3] = (__bf16)pa0.w;
    aF[4] = (__bf16)pa1.x; aF[5] = (__bf16)pa1.y; aF[6] = (__bf16)pa1.z; aF[7] = (__bf16)pa1.w;
#pragma unroll
    for (int t = 0; t < 8; ++t) {
      const bf16x8 bF = *(const bf16x8*)&W0P[(size_t)(((kk * 8 + t) * 64 + lane) * 8)];
      acc[t] = __builtin_amdgcn_mfma_f32_16x16x32_bf16(aF, bF, acc[t], 0, 0, 0);
    }
    pa0 = qa0; pa1 = qa1;
    qa0 = na0; qa1 = na1;
  }

  // ReLU + cvt -> h0s in A-operand layout (C/D: row=q*4+j, col=l16).
  // No barriers: each wave writes and reads only its own 16-row stripe.
#pragma unroll
  for (int t = 0; t < 8; ++t) {
#pragma unroll
    for (int j = 0; j < 4; ++j) {
      float v = acc[t][j];
      v = v > 0.f ? v : 0.f;
      h0s[(wave * 16 + q * 4 + j) * HPAD + t * 16 + l16] = (__bf16)v;
    }
  }

  f32x4 acc2[4];
#pragma unroll
  for (int t = 0; t < 4; ++t) acc2[t] = (f32x4){0.f, 0.f, 0.f, 0.f};
#pragma unroll
  for (int kk = 0; kk < HID / 32; ++kk) {
    const bf16x8 aF = *(const bf16x8*)&h0s[(wave * 16 + l16) * HPAD + kk * 32 + q * 8];
#pragma unroll
    for (int t = 0; t < 4; ++t) {
      const bf16x8 bF = *(const bf16x8*)&W1P[(size_t)(((kk * 4 + t) * 64 + lane) * 8)];
      acc2[t] = __builtin_amdgcn_mfma_f32_16x16x32_bf16(aF, bF, acc2[t], 0, 0, 0);
    }
  }

#pragma unroll
  for (int t = 0; t < 4; ++t) {
#pragma unroll
    for (int j = 0; j < 4; ++j) {
      const int grow = rb + wave * 16 + q * 4 + j;
      if (grow < NNODES)
        h1b[(size_t)grow * NCLS + t * 16 + l16] = (__bf16)acc2[t][j];
    }
  }
}

// ---------------------------------------------------------------------------
// SpMM gather, 4 rows per wave / 4 cols per lane (8B bf16x4 gathers).
// Each gather instruction moves 4 cache lines (one per row-group):
// 4x fewer vmem instructions per edge than 1-row/wave. Stores contiguous.
// Padding entries are {src=0,val=0} (memset) -> contribute 0.
// ---------------------------------------------------------------------------
template <typename OUT_T>
__global__ __launch_bounds__(256, 4)
void k_spmm(const int2* __restrict__ rowinfo, const int2* __restrict__ ecsr,
            const __bf16* __restrict__ x, OUT_T* __restrict__ y) {
  const int wid  = (blockIdx.x * 256 + threadIdx.x) >> 6;  // 25000 waves
  const int lane = threadIdx.x & 63;
  const int g    = lane >> 4;                              // row group 0..3
  const int l16  = lane & 15;
  const int row  = wid * 4 + g;                            // < NNODES (exact)
  const int c0   = l16 * 4;
  const int2 ri  = rowinfo[row];                           // {base, pdeg}
  const int base = ri.x, pdeg = ri.y;
  f32x4 acc = (f32x4){0.f, 0.f, 0.f, 0.f};
  for (int j = 0; j < pdeg; j += 8) {
    const int4 m0 = *(const int4*)&ecsr[base + j];
    const int4 m1 = *(const int4*)&ecsr[base + j + 2];
    const int4 m2 = *(const int4*)&ecsr[base + j + 4];
    const int4 m3 = *(const int4*)&ecsr[base + j + 6];
    const bf16x4 x0 = *(const bf16x4*)&x[(size_t)m0.x * NCLS + c0];
    const bf16x4 x1 = *(const bf16x4*)&x[(size_t)m0.z * NCLS + c0];
    const bf16x4 x2 = *(const bf16x4*)&x[(size_t)m1.x * NCLS + c0];
    const bf16x4 x3 = *(const bf16x4*)&x[(size_t)m1.z * NCLS + c0];
    const bf16x4 x4 = *(const bf16x4*)&x[(size_t)m2.x * NCLS + c0];
    const bf16x4 x5 = *(const bf16x4*)&x[(size_t)m2.z * NCLS + c0];
    const bf16x4 x6 = *(const bf16x4*)&x[(size_t)m3.x * NCLS + c0];
    const bf16x4 x7 = *(const bf16x4*)&x[(size_t)m3.z * NCLS + c0];
    const float v0 = __int_as_float(m0.y), v1 = __int_as_float(m0.w);
    const float v2 = __int_as_float(m1.y), v3 = __int_as_float(m1.w);
    const float v4 = __int_as_float(m2.y), v5 = __int_as_float(m2.w);
    const float v6 = __int_as_float(m3.y), v7 = __int_as_float(m3.w);
#pragma unroll
    for (int i = 0; i < 4; ++i) {
      acc[i] += v0 * (float)x0[i];
      acc[i] += v1 * (float)x1[i];
      acc[i] += v2 * (float)x2[i];
      acc[i] += v3 * (float)x3[i];
      acc[i] += v4 * (float)x4[i];
      acc[i] += v5 * (float)x5[i];
      acc[i] += v6 * (float)x6[i];
      acc[i] += v7 * (float)x7[i];
    }
  }
  if constexpr (sizeof(OUT_T) == 4) {
    float4 o;
    o.x = acc[0]; o.y = acc[1]; o.z = acc[2]; o.w = acc[3];
    *(float4*)&y[(size_t)row * NCLS + c0] = o;
  } else {
    bf16x4 o;
    o[0] = (__bf16)acc[0]; o[1] = (__bf16)acc[1];
    o[2] = (__bf16)acc[2]; o[3] = (__bf16)acc[3];
    *(bf16x4*)&y[(size_t)row * NCLS + c0] = o;
  }
}

// ---------------------------------------------------------------------------
extern "C" void kernel_launch(void* const* d_in, const int* in_sizes, int n_in,
                              void* d_out, int out_size, void* d_ws, size_t ws_size,
                              hipStream_t stream) {
  const float* feat = (const float*)d_in[0];
  const float* W0   = (const float*)d_in[1];
  const float* W1   = (const float*)d_in[2];
  const float* eval = (const float*)d_in[3];
  const int*   esrc = (const int*)d_in[4];
  const int*   edst = (const int*)d_in[5];
  float* out = (float*)d_out;

  // Workspace (~48.1 MB). [ecsr | deg | galloc] are contiguous -> ONE memset.
  // h1b lives in d_out (live scatter_gemm -> spmm1; final spmm2 overwrites).
  char* p = (char*)d_ws;
  int2*   ecsr    = (int2*)p;   p += (size_t)ECSR_CAP * 8;      // 33,554,432
  int*    deg     = (int*)p;    p += 401408;                    // 100,352 ints
  int*    galloc  = (int*)p;    p += 64;
  int*    cur     = (int*)p;    p += 401408;
  int2*   rowinfo = (int2*)p;   p += 800768;                    // 100,096 int2
  __bf16* W0P     = (__bf16*)p; p += 131072;
  __bf16* W1P     = (__bf16*)p; p += 16384;
  __bf16* h2b     = (__bf16*)p; p += 12800000;
  __bf16* h1b     = (__bf16*)d_out;                             // 12.8MB scratch

  // Zero ecsr (padding entries must be {0,0}) + deg + galloc in one shot.
  hipMemsetAsync(ecsr, 0, (size_t)ECSR_CAP * 8 + 401408 + 64, stream);
  k_count_wcvt <<<NCHUNKB + 1, 256, 0, stream>>>(edst, deg, W0, W1, W0P, W1P);
  k_lscan      <<<NSCAN, 512, 0, stream>>>(deg, galloc, rowinfo, cur);
  k_scatter_gemm<<<NCHUNKB + (NNODES + 63) / 64, 256, 0, stream>>>(
      edst, esrc, eval, cur, ecsr, feat, W0P, W1P, h1b);

  k_spmm<__bf16><<<NNODES / 16, 256, 0, stream>>>(rowinfo, ecsr, h1b, h2b);
  k_spmm<float> <<<NNODES / 16, 256, 0, stream>>>(rowinfo, ecsr, h2b, out);

  (void)in_sizes; (void)n_in; (void)out_size; (void)ws_size;
}